// Round 1
// baseline (297.079 us; speedup 1.0000x reference)
//
#include <hip/hip_runtime.h>

// ---------------- problem constants ----------------
#define B_     32
#define C_     2
#define L_     160000
#define NFFT   2048
#define HOP    512
#define PAD    1024
#define LPAD   162048            // L_ + 2*PAD
#define T_     313               // frames
#define BC     64                // B_*C_
#define M_     20032             // BC*T_
#define KCH    1025              // output channels per (real|imag)
#define N2     2050              // real+imag stacked
#define NP     2176              // N padded to 17*128
#define K_     2048
#define OUT_HALF 20532800UL      // M_*KCH

typedef __attribute__((ext_vector_type(8))) short short8;
typedef __attribute__((ext_vector_type(4))) float f32x4;

static __device__ __forceinline__ short f2bf(float f) {
  union { float f; unsigned u; } v; v.f = f;
  unsigned u = v.u;
  unsigned r = (u + 0x7fffu + ((u >> 16) & 1u)) >> 16;  // RNE
  return (short)r;
}

// ---------------- prep: reflect-padded x as bf16 ----------------
__global__ void prep_xpad(const float* __restrict__ x, short* __restrict__ xpad) {
  int i = blockIdx.x * 256 + threadIdx.x;       // < 64*162048 = 10,371,072
  int bc = i / LPAD;
  int p  = i - bc * LPAD;
  int j  = p - PAD;
  j = j < 0 ? -j : j;
  j = j >= L_ ? (2 * L_ - 2 - j) : j;
  xpad[i] = f2bf(x[bc * L_ + j]);
}

// ---------------- prep: W_real || W_imag as bf16, padded ----------------
__global__ void prep_wb(const float* __restrict__ wr, const float* __restrict__ wi,
                        short* __restrict__ wb) {
  int i = blockIdx.x * 256 + threadIdx.x;       // < 2176*2048 = 4,456,448
  int n = i >> 11;
  int c = i & 2047;
  float v = 0.f;
  if (n < KCH)      v = wr[n * K_ + c];
  else if (n < N2)  v = wi[(n - KCH) * K_ + c];
  wb[i] = f2bf(v);
}

// ---------------- GEMM: m97 structure, 128x128 tile, BK=64 ----------------
#define GLOAD16(g, l) __builtin_amdgcn_global_load_lds(                        \
    (const __attribute__((address_space(1))) void*)(g),                        \
    (__attribute__((address_space(3))) void*)(l), 16, 0, 0)

__global__ __launch_bounds__(256, 2) void stft_gemm(const short* __restrict__ xpad,
                                                    const short* __restrict__ wb,
                                                    float* __restrict__ out) {
  __shared__ short ldsA[128 * 64];
  __shared__ short ldsB[128 * 64];
  const int tid  = threadIdx.x;
  const int lane = tid & 63;
  const int wid  = tid >> 6;
  const int nt = blockIdx.x;          // 0..16
  const int mt = blockIdx.y;          // 0..156
  const int M0 = mt * 128, N0 = nt * 128;

  // staging source bases: instruction ii covers LDS rows (wid*4+ii)*8 .. +8
  // lane -> row = +lane/8, col = (lane&7)*8  (contiguous 16B per lane)
  const short* asrc[4];
  const short* bsrc[4];
  const int c8 = (lane & 7) * 8;
  #pragma unroll
  for (int ii = 0; ii < 4; ++ii) {
    int r = wid * 32 + ii * 8 + (lane >> 3);
    int m = M0 + r; if (m > M_ - 1) m = M_ - 1;   // clamp tail tile (not stored)
    int bc = m / T_;
    int t  = m - bc * T_;
    asrc[ii] = xpad + ((size_t)bc * LPAD + (size_t)t * HOP + c8);
    int n = N0 + r;                               // < 2176 always
    bsrc[ii] = wb + ((size_t)n * K_ + c8);
  }

  f32x4 acc[4][4];
  #pragma unroll
  for (int i = 0; i < 4; ++i)
    #pragma unroll
    for (int j = 0; j < 4; ++j) acc[i][j] = (f32x4){0.f, 0.f, 0.f, 0.f};

  const int wr = wid >> 1, wc = wid & 1;   // 2x2 wave grid, each wave 64x64
  const int fr = lane & 15;                // fragment row (A) / col (B)
  const int fo = (lane >> 4) * 8;          // k sub-offset within 32-block

  for (int kk = 0; kk < K_ / 64; ++kk) {
    const int ko = kk * 64;
    #pragma unroll
    for (int ii = 0; ii < 4; ++ii) {
      GLOAD16(asrc[ii] + ko, &ldsA[(wid * 4 + ii) * 512]);
      GLOAD16(bsrc[ii] + ko, &ldsB[(wid * 4 + ii) * 512]);
    }
    __syncthreads();   // compiler drains vmcnt before barrier

    short8 af[4][2], bf[4][2];
    #pragma unroll
    for (int i = 0; i < 4; ++i) {
      #pragma unroll
      for (int ks = 0; ks < 2; ++ks) {
        af[i][ks] = *(const short8*)&ldsA[(wr * 64 + i * 16 + fr) * 64 + ks * 32 + fo];
        bf[i][ks] = *(const short8*)&ldsB[(wc * 64 + i * 16 + fr) * 64 + ks * 32 + fo];
      }
    }
    #pragma unroll
    for (int i = 0; i < 4; ++i)
      #pragma unroll
      for (int j = 0; j < 4; ++j)
        #pragma unroll
        for (int ks = 0; ks < 2; ++ks)
          acc[i][j] = __builtin_amdgcn_mfma_f32_16x16x32_bf16(af[i][ks], bf[j][ks],
                                                              acc[i][j], 0, 0, 0);
    __syncthreads();   // LDS reuse next K-step
  }

  // epilogue: C/D layout col=lane&15, row=(lane>>4)*4+reg  [m89/m91 verified]
  const int col0 = N0 + wc * 64 + fr;
  const int row0 = M0 + wr * 64 + (lane >> 4) * 4;
  #pragma unroll
  for (int i = 0; i < 4; ++i) {
    #pragma unroll
    for (int r = 0; r < 4; ++r) {
      int gm = row0 + i * 16 + r;
      if (gm < M_) {
        size_t rb = (size_t)gm * KCH;
        #pragma unroll
        for (int j = 0; j < 4; ++j) {
          int gn = col0 + j * 16;
          float v = acc[i][j][r];
          if (gn < KCH)        out[rb + gn] = v;              // real
          else if (gn < N2)    out[OUT_HALF + rb + (gn - KCH)] = v;  // imag
        }
      }
    }
  }
}

// ---------------- launcher ----------------
extern "C" void kernel_launch(void* const* d_in, const int* in_sizes, int n_in,
                              void* d_out, int out_size, void* d_ws, size_t ws_size,
                              hipStream_t stream) {
  const float* x  = (const float*)d_in[0];
  const float* Wr = (const float*)d_in[1];
  const float* Wi = (const float*)d_in[2];
  float* out = (float*)d_out;

  short* xpad = (short*)d_ws;                           // 10,371,072 bf16 = 20.7 MB
  short* wbuf = (short*)d_ws + (size_t)BC * LPAD;       //  4,456,448 bf16 =  8.9 MB

  prep_xpad<<<(BC * LPAD) / 256, 256, 0, stream>>>(x, xpad);
  prep_wb<<<(NP * K_) / 256, 256, 0, stream>>>(Wr, Wi, wbuf);

  dim3 grid(NP / 128, (M_ + 127) / 128);                // 17 x 157
  stft_gemm<<<grid, 256, 0, stream>>>(xpad, wbuf, out);
}

// Round 2
// 236.731 us; speedup vs baseline: 1.2549x; 1.2549x over previous
//
#include <hip/hip_runtime.h>

// ---------------- problem constants ----------------
#define B_     32
#define C_     2
#define L_     160000
#define HOP    512
#define PAD    1024
#define LPAD   162048            // L_ + 2*PAD
#define T_     313               // frames
#define BC     64                // B_*C_
#define M_     20032             // BC*T_
#define KCH    1025              // output channels per (real|imag)
#define N2     2050              // real+imag stacked
#define NP     2304              // N padded to 9*256
#define K_     2048
#define OUT_HALF 20532800UL      // M_*KCH
#define NKT    64                // K_/32 K-tiles
#define MT     79                // ceil(M_/256)
#define NT     9                 // NP/256

typedef __attribute__((ext_vector_type(8))) short short8;
typedef __attribute__((ext_vector_type(4))) float f32x4;

static __device__ __forceinline__ short f2bf(float f) {
  union { float f; unsigned u; } v; v.f = f;
  unsigned u = v.u;
  unsigned r = (u + 0x7fffu + ((u >> 16) & 1u)) >> 16;  // RNE
  return (short)r;
}

// ---------------- prep: reflect-padded x as bf16 (vectorized) ----------------
__global__ void prep_xpad(const float* __restrict__ x, short* __restrict__ xpad) {
  int v = blockIdx.x * 256 + threadIdx.x;          // < 64 * 20256 = 1,296,384
  int bc = v / 20256;
  int p8 = (v - bc * 20256) * 8;
  const float* src = x + (size_t)bc * L_;
  int j0 = p8 - PAD;
  short8 o;
  if (j0 >= 0 && j0 + 7 < L_) {
    float4 a = *(const float4*)(src + j0);
    float4 b = *(const float4*)(src + j0 + 4);
    o[0]=f2bf(a.x); o[1]=f2bf(a.y); o[2]=f2bf(a.z); o[3]=f2bf(a.w);
    o[4]=f2bf(b.x); o[5]=f2bf(b.y); o[6]=f2bf(b.z); o[7]=f2bf(b.w);
  } else {
    #pragma unroll
    for (int r = 0; r < 8; ++r) {
      int j = j0 + r;
      j = j < 0 ? -j : j;
      j = j >= L_ ? 2 * L_ - 2 - j : j;
      o[r] = f2bf(src[j]);
    }
  }
  *(short8*)&xpad[(size_t)bc * LPAD + p8] = o;
}

// ---------------- prep: W_real || W_imag as bf16, padded to NP rows ----------------
__global__ void prep_wb(const float* __restrict__ wr, const float* __restrict__ wi,
                        short* __restrict__ wb) {
  int v = blockIdx.x * 256 + threadIdx.x;          // < 2304*256 = 589,824
  int n = v >> 8;
  int c8 = (v & 255) * 8;
  short8 o;
  const float* src = nullptr;
  if (n < KCH)      src = wr + (size_t)n * K_ + c8;
  else if (n < N2)  src = wi + (size_t)(n - KCH) * K_ + c8;
  if (src) {
    float4 a = *(const float4*)src;
    float4 b = *(const float4*)(src + 4);
    o[0]=f2bf(a.x); o[1]=f2bf(a.y); o[2]=f2bf(a.z); o[3]=f2bf(a.w);
    o[4]=f2bf(b.x); o[5]=f2bf(b.y); o[6]=f2bf(b.z); o[7]=f2bf(b.w);
  } else {
    o = (short8){0,0,0,0,0,0,0,0};
  }
  *(short8*)&wb[(size_t)n * K_ + c8] = o;
}

// ---------------- GEMM: 256x256 tile, BK=32, 4-slot counted-vmcnt pipeline ----------------
#define GLOAD16(g, l) __builtin_amdgcn_global_load_lds(                        \
    (const __attribute__((address_space(1))) void*)(g),                        \
    (__attribute__((address_space(3))) void*)(l), 16, 0, 0)

// barrier with full compiler fences (block IR + MIR motion across it)
#define BARRIER() do {                                                         \
    asm volatile("" ::: "memory");                                             \
    __builtin_amdgcn_sched_barrier(0);                                         \
    __builtin_amdgcn_s_barrier();                                              \
    __builtin_amdgcn_sched_barrier(0);                                         \
    asm volatile("" ::: "memory");                                             \
  } while (0)

__global__ __launch_bounds__(512, 2) void stft_gemm(const short* __restrict__ xpad,
                                                    const short* __restrict__ wb,
                                                    float* __restrict__ out) {
  // 4 slots x (A[256][32] + B[256][32]) bf16 = 4 x 32 KB = 128 KB
  __shared__ short lds[65536];
  const int tid  = threadIdx.x;
  const int lane = tid & 63;
  const int wid  = tid >> 6;          // 0..7
  const int nt = blockIdx.x;          // 0..8
  const int mt = blockIdx.y;          // 0..78
  const int M0 = mt * 256, N0 = nt * 256;

  // ---- staging setup: per thread 2 A-loads + 2 B-loads per K-tile ----
  // instr j covers tile rows wid*32 + j*16 + (lane>>2); lane&3 picks 16B chunk.
  // LDS dest is linear; global source column is inverse-swizzled (rule 21):
  // physical[row][cb] = logical[row][cb ^ ((row&6)<<3 bytes)]
  const short* aS[2];
  const short* bS[2];
  int ldsOffA[2], ldsOffB[2];
  #pragma unroll
  for (int j = 0; j < 2; ++j) {
    int row = wid * 32 + j * 16 + (lane >> 2);
    int colswz = ((lane & 3) * 8) ^ ((row & 6) << 2);   // elements
    int m = M0 + row; if (m > M_ - 1) m = M_ - 1;       // clamp tail (not stored)
    int bc = m / T_;
    int t  = m - bc * T_;
    aS[j] = xpad + (size_t)bc * LPAD + (size_t)t * HOP + colswz;
    int n = N0 + row;                                    // < 2304 always
    bS[j] = wb + (size_t)n * K_ + colswz;
    ldsOffA[j] = (wid * 2 + j) * 1024 + lane * 16;       // bytes within A area
    ldsOffB[j] = 16384 + (wid * 2 + j) * 1024 + lane * 16;
  }

  // ---- fragment read offsets (swizzled ds_read) ----
  const int wr = wid >> 2, wc = wid & 3;   // 2M x 4N wave grid; per-wave 128x64
  const int fr = lane & 15;
  const int xorb = ((lane >> 4) * 16) ^ ((fr & 6) << 3);  // byte col within 64B row
  int aoff[8], boff[4];
  #pragma unroll
  for (int i = 0; i < 8; ++i) aoff[i] = (wr * 128 + i * 16 + fr) * 64 + xorb;
  #pragma unroll
  for (int j = 0; j < 4; ++j) boff[j] = 16384 + (wc * 64 + j * 16 + fr) * 64 + xorb;

  f32x4 acc[8][4];
  #pragma unroll
  for (int i = 0; i < 8; ++i)
    #pragma unroll
    for (int j = 0; j < 4; ++j) acc[i][j] = (f32x4){0.f, 0.f, 0.f, 0.f};

  // ---- prologue: stage K-tiles 0,1,2 into slots 0,1,2 (12 loads in flight) ----
  #pragma unroll
  for (int kt = 0; kt < 3; ++kt) {
    char* slot = (char*)lds + kt * 32768;
    const int ko = kt * 32;
    GLOAD16(aS[0] + ko, slot + ldsOffA[0]);
    GLOAD16(aS[1] + ko, slot + ldsOffA[1]);
    GLOAD16(bS[0] + ko, slot + ldsOffB[0]);
    GLOAD16(bS[1] + ko, slot + ldsOffB[1]);
  }

  // ---- main loop: one K-tile per iteration, 2 phases of 16 MFMA ----
  for (int kt = 0; kt < NKT; ++kt) {
    char* slotr = (char*)lds + (kt & 3) * 32768;
    // complete tile kt (leave kt+1, kt+2 = 8 loads in flight; never 0 until tail)
    if (kt < NKT - 2)       asm volatile("s_waitcnt vmcnt(8)" ::: "memory");
    else if (kt == NKT - 2) asm volatile("s_waitcnt vmcnt(4)" ::: "memory");
    else                    asm volatile("s_waitcnt vmcnt(0)" ::: "memory");
    BARRIER();   // all waves: tile kt landed; slot (kt+3)&3 reads finished last iter

    const bool doStage = (kt <= NKT - 4);
    char* slotw = (char*)lds + ((kt + 3) & 3) * 32768;
    const int kos = (kt + 3) * 32;

    // ---- phase A: stage A-half of kt+3; read m-frags 0-3 + all B; 16 MFMA ----
    if (doStage) {
      GLOAD16(aS[0] + kos, slotw + ldsOffA[0]);
      GLOAD16(aS[1] + kos, slotw + ldsOffA[1]);
    }
    short8 af[4], bf[4];
    #pragma unroll
    for (int i = 0; i < 4; ++i) af[i] = *(const short8*)(slotr + aoff[i]);
    #pragma unroll
    for (int j = 0; j < 4; ++j) bf[j] = *(const short8*)(slotr + boff[j]);
    BARRIER();
    __builtin_amdgcn_s_setprio(1);
    #pragma unroll
    for (int i = 0; i < 4; ++i)
      #pragma unroll
      for (int j = 0; j < 4; ++j)
        acc[i][j] = __builtin_amdgcn_mfma_f32_16x16x32_bf16(af[i], bf[j],
                                                            acc[i][j], 0, 0, 0);
    __builtin_amdgcn_s_setprio(0);
    BARRIER();

    // ---- phase B: stage B-half of kt+3; read m-frags 4-7 (reuse bf); 16 MFMA ----
    if (doStage) {
      GLOAD16(bS[0] + kos, slotw + ldsOffB[0]);
      GLOAD16(bS[1] + kos, slotw + ldsOffB[1]);
    }
    short8 af2[4];
    #pragma unroll
    for (int i = 0; i < 4; ++i) af2[i] = *(const short8*)(slotr + aoff[4 + i]);
    BARRIER();
    __builtin_amdgcn_s_setprio(1);
    #pragma unroll
    for (int i = 0; i < 4; ++i)
      #pragma unroll
      for (int j = 0; j < 4; ++j)
        acc[4 + i][j] = __builtin_amdgcn_mfma_f32_16x16x32_bf16(af2[i], bf[j],
                                                                acc[4 + i][j], 0, 0, 0);
    __builtin_amdgcn_s_setprio(0);
    BARRIER();
  }

  // ---- epilogue: C/D layout col=lane&15, row=(lane>>4)*4+reg ----
  const int col0 = N0 + wc * 64 + (lane & 15);
  const int row0 = M0 + wr * 128 + ((lane >> 4) << 2);
  #pragma unroll
  for (int i = 0; i < 8; ++i) {
    #pragma unroll
    for (int r = 0; r < 4; ++r) {
      int gm = row0 + i * 16 + r;
      if (gm < M_) {
        size_t rb = (size_t)gm * KCH;
        #pragma unroll
        for (int j = 0; j < 4; ++j) {
          int gn = col0 + j * 16;
          float v = acc[i][j][r];
          if (gn < KCH)     out[rb + gn] = v;                       // real
          else if (gn < N2) out[OUT_HALF + rb + (gn - KCH)] = v;    // imag
        }
      }
    }
  }
}

// ---------------- launcher ----------------
extern "C" void kernel_launch(void* const* d_in, const int* in_sizes, int n_in,
                              void* d_out, int out_size, void* d_ws, size_t ws_size,
                              hipStream_t stream) {
  const float* x  = (const float*)d_in[0];
  const float* Wr = (const float*)d_in[1];
  const float* Wi = (const float*)d_in[2];
  float* out = (float*)d_out;

  short* xpad = (short*)d_ws;                           // 10,371,072 bf16 = 20.7 MB
  short* wbuf = (short*)d_ws + (size_t)BC * LPAD;       //  4,718,592 bf16 =  9.4 MB

  prep_xpad<<<5064, 256, 0, stream>>>(x, xpad);         // 5064*256 = 1,296,384
  prep_wb<<<2304, 256, 0, stream>>>(Wr, Wi, wbuf);      // 2304*256 = 589,824

  dim3 grid(NT, MT);                                    // 9 x 79
  stft_gemm<<<grid, 512, 0, stream>>>(xpad, wbuf, out);
}

// Round 3
// 225.628 us; speedup vs baseline: 1.3167x; 1.0492x over previous
//
#include <hip/hip_runtime.h>

// ---------------- problem constants ----------------
#define B_     32
#define C_     2
#define L_     160000
#define HOP    512
#define PAD    1024
#define LPAD   162048            // L_ + 2*PAD
#define T_     313               // frames
#define BC     64                // B_*C_
#define M_     20032             // BC*T_
#define KCH    1025              // output channels per (real|imag)
#define N2     2050              // real+imag stacked
#define NP     2304              // N padded to 9*256
#define K_     2048
#define OUT_HALF 20532800UL      // M_*KCH
#define NKT    64                // K_/32 K-tiles
#define MT     79                // ceil(M_/256)
#define NT     9                 // NP/256
#define NWG    711               // MT*NT

typedef __attribute__((ext_vector_type(8))) short short8;
typedef __attribute__((ext_vector_type(4))) float f32x4;

static __device__ __forceinline__ short f2bf(float f) {
  union { float f; unsigned u; } v; v.f = f;
  unsigned u = v.u;
  unsigned r = (u + 0x7fffu + ((u >> 16) & 1u)) >> 16;  // RNE
  return (short)r;
}

// ---------------- prep: reflect-padded x as bf16 (vectorized) ----------------
__global__ void prep_xpad(const float* __restrict__ x, short* __restrict__ xpad) {
  int v = blockIdx.x * 256 + threadIdx.x;          // < 64 * 20256 = 1,296,384
  int bc = v / 20256;
  int p8 = (v - bc * 20256) * 8;
  const float* src = x + (size_t)bc * L_;
  int j0 = p8 - PAD;
  short8 o;
  if (j0 >= 0 && j0 + 7 < L_) {
    float4 a = *(const float4*)(src + j0);
    float4 b = *(const float4*)(src + j0 + 4);
    o[0]=f2bf(a.x); o[1]=f2bf(a.y); o[2]=f2bf(a.z); o[3]=f2bf(a.w);
    o[4]=f2bf(b.x); o[5]=f2bf(b.y); o[6]=f2bf(b.z); o[7]=f2bf(b.w);
  } else {
    #pragma unroll
    for (int r = 0; r < 8; ++r) {
      int j = j0 + r;
      j = j < 0 ? -j : j;
      j = j >= L_ ? 2 * L_ - 2 - j : j;
      o[r] = f2bf(src[j]);
    }
  }
  *(short8*)&xpad[(size_t)bc * LPAD + p8] = o;
}

// ---------------- prep: W_real || W_imag as bf16, padded to NP rows ----------------
__global__ void prep_wb(const float* __restrict__ wr, const float* __restrict__ wi,
                        short* __restrict__ wb) {
  int v = blockIdx.x * 256 + threadIdx.x;          // < 2304*256 = 589,824
  int n = v >> 8;
  int c8 = (v & 255) * 8;
  short8 o;
  const float* src = nullptr;
  if (n < KCH)      src = wr + (size_t)n * K_ + c8;
  else if (n < N2)  src = wi + (size_t)(n - KCH) * K_ + c8;
  if (src) {
    float4 a = *(const float4*)src;
    float4 b = *(const float4*)(src + 4);
    o[0]=f2bf(a.x); o[1]=f2bf(a.y); o[2]=f2bf(a.z); o[3]=f2bf(a.w);
    o[4]=f2bf(b.x); o[5]=f2bf(b.y); o[6]=f2bf(b.z); o[7]=f2bf(b.w);
  } else {
    o = (short8){0,0,0,0,0,0,0,0};
  }
  *(short8*)&wb[(size_t)n * K_ + c8] = o;
}

// ---------------- GEMM: 256x256 tile, BK=32, 4-slot counted-vmcnt pipeline ----------------
#define GLOAD16(g, l) __builtin_amdgcn_global_load_lds(                        \
    (const __attribute__((address_space(1))) void*)(g),                        \
    (__attribute__((address_space(3))) void*)(l), 16, 0, 0)

__global__ __launch_bounds__(512, 2) void stft_gemm(const short* __restrict__ xpad,
                                                    const short* __restrict__ wb,
                                                    float* __restrict__ out) {
  // 4 slots x (A[256][32] + B[256][32]) bf16 = 4 x 32 KB = 128 KB
  __shared__ short lds[65536];
  const int tid  = threadIdx.x;
  const int lane = tid & 63;
  const int wid  = tid >> 6;          // 0..7

  // ---- bijective XCD-chunked remap (T1, m204): id%8 = XCD round-robin ----
  // XCD k walks contiguous work ids w; w column-major (nt outer, mt inner)
  // so each XCD keeps one 1MB B-tile L2-resident and streams A-panels once.
  const int id  = blockIdx.x;                  // 0..710
  const int xcd = id & 7, pos = id >> 3;       // q=88, r=7
  const int w   = (xcd < 7 ? xcd * 89 : 623) + pos;
  const int nt  = w / MT;
  const int mt  = w - nt * MT;
  const int M0 = mt * 256, N0 = nt * 256;

  // ---- staging setup: per thread 2 A-loads + 2 B-loads per K-tile ----
  // instr j covers tile rows wid*32 + j*16 + (lane>>2); lane&3 picks 16B chunk.
  // LDS dest is linear; global source column is inverse-swizzled (rule 21):
  // physical[row][cb] = logical[row][cb ^ ((row&6)<<3 bytes)]
  const short* aS[2];
  const short* bS[2];
  int ldsOffA[2], ldsOffB[2];
  #pragma unroll
  for (int j = 0; j < 2; ++j) {
    int row = wid * 32 + j * 16 + (lane >> 2);
    int colswz = ((lane & 3) * 8) ^ ((row & 6) << 2);   // elements
    int m = M0 + row; if (m > M_ - 1) m = M_ - 1;       // clamp tail (not stored)
    int bc = m / T_;
    int t  = m - bc * T_;
    aS[j] = xpad + (size_t)bc * LPAD + (size_t)t * HOP + colswz;
    int n = N0 + row;                                    // < 2304 always
    bS[j] = wb + (size_t)n * K_ + colswz;
    ldsOffA[j] = (wid * 2 + j) * 1024 + lane * 16;       // bytes within A area
    ldsOffB[j] = 16384 + (wid * 2 + j) * 1024 + lane * 16;
  }

  // ---- fragment read offsets (swizzled ds_read) ----
  const int wr = wid >> 2, wc = wid & 3;   // 2M x 4N wave grid; per-wave 128x64
  const int fr = lane & 15;
  const int xorb = ((lane >> 4) * 16) ^ ((fr & 6) << 3);  // byte col within 64B row
  int aoff[8], boff[4];
  #pragma unroll
  for (int i = 0; i < 8; ++i) aoff[i] = (wr * 128 + i * 16 + fr) * 64 + xorb;
  #pragma unroll
  for (int j = 0; j < 4; ++j) boff[j] = 16384 + (wc * 64 + j * 16 + fr) * 64 + xorb;

  f32x4 acc[8][4];
  #pragma unroll
  for (int i = 0; i < 8; ++i)
    #pragma unroll
    for (int j = 0; j < 4; ++j) acc[i][j] = (f32x4){0.f, 0.f, 0.f, 0.f};

  // ---- prologue: stage K-tiles 0,1,2 into slots 0,1,2 (12 loads in flight) ----
  #pragma unroll
  for (int kt = 0; kt < 3; ++kt) {
    char* slot = (char*)lds + kt * 32768;
    const int ko = kt * 32;
    GLOAD16(aS[0] + ko, slot + ldsOffA[0]);
    GLOAD16(aS[1] + ko, slot + ldsOffA[1]);
    GLOAD16(bS[0] + ko, slot + ldsOffB[0]);
    GLOAD16(bS[1] + ko, slot + ldsOffB[1]);
  }

  // ---- main loop: one K-tile per iteration, 2 phases of 16 MFMA ----
  for (int kt = 0; kt < NKT; ++kt) {
    char* slotr = (char*)lds + (kt & 3) * 32768;
    // complete tile kt (leave kt+1, kt+2 = 8 loads in flight; never 0 until tail)
    if (kt < NKT - 2)       asm volatile("s_waitcnt vmcnt(8)" ::: "memory");
    else if (kt == NKT - 2) asm volatile("s_waitcnt vmcnt(4)" ::: "memory");
    else                    asm volatile("s_waitcnt vmcnt(0)" ::: "memory");
    __builtin_amdgcn_s_barrier();  // tile kt landed in all waves; slot (kt+3)&3 free

    const bool doStage = (kt <= NKT - 4);
    char* slotw = (char*)lds + ((kt + 3) & 3) * 32768;
    const int kos = (kt + 3) * 32;

    // ---- phase A: stage A-half of kt+3; read m-frags 0-3 + all B; 16 MFMA ----
    if (doStage) {
      GLOAD16(aS[0] + kos, slotw + ldsOffA[0]);
      GLOAD16(aS[1] + kos, slotw + ldsOffA[1]);
    }
    short8 af[4], bf[4];
    #pragma unroll
    for (int i = 0; i < 4; ++i) af[i] = *(const short8*)(slotr + aoff[i]);
    #pragma unroll
    for (int j = 0; j < 4; ++j) bf[j] = *(const short8*)(slotr + boff[j]);
    __builtin_amdgcn_s_barrier();
    __builtin_amdgcn_s_setprio(1);
    #pragma unroll
    for (int i = 0; i < 4; ++i)
      #pragma unroll
      for (int j = 0; j < 4; ++j)
        acc[i][j] = __builtin_amdgcn_mfma_f32_16x16x32_bf16(af[i], bf[j],
                                                            acc[i][j], 0, 0, 0);
    __builtin_amdgcn_s_setprio(0);
    __builtin_amdgcn_s_barrier();

    // ---- phase B: stage B-half of kt+3; read m-frags 4-7 (reuse bf); 16 MFMA ----
    if (doStage) {
      GLOAD16(bS[0] + kos, slotw + ldsOffB[0]);
      GLOAD16(bS[1] + kos, slotw + ldsOffB[1]);
    }
    short8 af2[4];
    #pragma unroll
    for (int i = 0; i < 4; ++i) af2[i] = *(const short8*)(slotr + aoff[4 + i]);
    __builtin_amdgcn_s_barrier();
    __builtin_amdgcn_s_setprio(1);
    #pragma unroll
    for (int i = 0; i < 4; ++i)
      #pragma unroll
      for (int j = 0; j < 4; ++j)
        acc[4 + i][j] = __builtin_amdgcn_mfma_f32_16x16x32_bf16(af2[i], bf[j],
                                                                acc[4 + i][j], 0, 0, 0);
    __builtin_amdgcn_s_setprio(0);
    __builtin_amdgcn_s_barrier();
  }

  // ---- epilogue: C/D layout col=lane&15, row=(lane>>4)*4+reg ----
  const int col0 = N0 + wc * 64 + (lane & 15);
  const int row0 = M0 + wr * 128 + ((lane >> 4) << 2);
  #pragma unroll
  for (int i = 0; i < 8; ++i) {
    #pragma unroll
    for (int r = 0; r < 4; ++r) {
      int gm = row0 + i * 16 + r;
      if (gm < M_) {
        size_t rb = (size_t)gm * KCH;
        #pragma unroll
        for (int j = 0; j < 4; ++j) {
          int gn = col0 + j * 16;
          float v = acc[i][j][r];
          if (gn < KCH)     out[rb + gn] = v;                       // real
          else if (gn < N2) out[OUT_HALF + rb + (gn - KCH)] = v;    // imag
        }
      }
    }
  }
}

// ---------------- launcher ----------------
extern "C" void kernel_launch(void* const* d_in, const int* in_sizes, int n_in,
                              void* d_out, int out_size, void* d_ws, size_t ws_size,
                              hipStream_t stream) {
  const float* x  = (const float*)d_in[0];
  const float* Wr = (const float*)d_in[1];
  const float* Wi = (const float*)d_in[2];
  float* out = (float*)d_out;

  short* xpad = (short*)d_ws;                           // 10,371,072 bf16 = 20.7 MB
  short* wbuf = (short*)d_ws + (size_t)BC * LPAD;       //  4,718,592 bf16 =  9.4 MB

  prep_xpad<<<5064, 256, 0, stream>>>(x, xpad);         // 5064*256 = 1,296,384
  prep_wb<<<2304, 256, 0, stream>>>(Wr, Wi, wbuf);      // 2304*256 = 589,824

  stft_gemm<<<NWG, 512, 0, stream>>>(xpad, wbuf, out);
}